// Round 18
// baseline (268.402 us; speedup 1.0000x reference)
//
#include <hip/hip_runtime.h>
#include <cmath>

typedef __attribute__((ext_vector_type(8))) short short8;
typedef __attribute__((ext_vector_type(4))) float f32x4;
typedef __attribute__((ext_vector_type(4))) unsigned short us4;
typedef unsigned short u16;

#define BATCH 8192
static constexpr size_t BH = (size_t)BATCH * 256;
#define LPAD 264  // u16 LDS row stride (528 B)

__device__ __forceinline__ u16 f2bf(float f) {
    union { float f; unsigned u; } v; v.f = f;
    unsigned r = v.u + 0x7FFFu + ((v.u >> 16) & 1u);
    return (u16)(r >> 16);
}
__device__ __forceinline__ float bf2f(u16 u) {
    union { unsigned u; float f; } v; v.u = ((unsigned)u) << 16;
    return v.f;
}
__device__ __forceinline__ float sigmoidf_(float x) {
    return 1.f / (1.f + __expf(-x));
}
__device__ __forceinline__ short8 cvt8(const float* p) {
    f32x4 lo = *(const f32x4*)p, hi = *(const f32x4*)(p + 4);
    short8 t;
    t[0] = (short)f2bf(lo[0]); t[1] = (short)f2bf(lo[1]);
    t[2] = (short)f2bf(lo[2]); t[3] = (short)f2bf(lo[3]);
    t[4] = (short)f2bf(hi[0]); t[5] = (short)f2bf(hi[1]);
    t[6] = (short)f2bf(hi[2]); t[7] = (short)f2bf(hi[3]);
    return t;
}
__device__ __forceinline__ float dot4(const f32x4& a, const float* b) {
    return a[0] * b[0] + a[1] * b[1] + a[2] * b[2] + a[3] * b[3];
}

// ---------------- weight conversion ----------------
// dst layout (u16 units, 65536 per chunk):
//  c0: embed_w | c1..4: wtn[l] | c5..8: wsn[l] | c9..12: wt[l][512:768]
//  c13..16: ws[l][0:256] | c17..20: ws[l][512:768] | c21: out_w
__global__ __launch_bounds__(256) void convert_weights(
    const float* __restrict__ embed_w, const float* __restrict__ wtn,
    const float* __restrict__ wsn, const float* __restrict__ wt,
    const float* __restrict__ ws, const float* __restrict__ out_w,
    u16* __restrict__ dst)
{
    int idx = blockIdx.x * 256 + threadIdx.x;
    int e = idx * 4;
    if (e >= 22 * 65536) return;
    int c = e >> 16, o = e & 65535;
    const float* src;
    if (c == 0)      src = embed_w + o;
    else if (c < 5)  src = wtn + (size_t)(c - 1) * 65536 + o;
    else if (c < 9)  src = wsn + (size_t)(c - 5) * 65536 + o;
    else if (c < 13) src = wt + (size_t)(c - 9) * 768 * 256 + 512 * 256 + o;
    else if (c < 17) src = ws + (size_t)(c - 13) * 768 * 256 + o;
    else if (c < 21) src = ws + (size_t)(c - 17) * 768 * 256 + 512 * 256 + o;
    else             src = out_w + o;
    f32x4 v = *(const f32x4*)src;
    us4 r;
#pragma unroll
    for (int j = 0; j < 4; ++j) r[j] = f2bf(v[j]);
    *(us4*)(dst + e) = r;
}

// ---------------- gemm_one: C[8192,256] = A @ W^T + b ----------------
// block 256 thr (4 waves): M=32, N=128; wave w -> 32 cols. A staged in LDS.
template<bool A_F32, int ACT>
__global__ __launch_bounds__(256, 4) void gemm_one(
    const void* __restrict__ Ap, const u16* __restrict__ W,
    const float* __restrict__ bias, void* __restrict__ Cp)
{
    __shared__ __align__(16) u16 A[32][LPAD];
    const int t = threadIdx.x;
    const int row0 = blockIdx.x * 32;
    {
        int r = t >> 3, c0 = (t & 7) * 32;
        if constexpr (A_F32) {
            const float* p = (const float*)Ap + (size_t)(row0 + r) * 256 + c0;
#pragma unroll
            for (int j = 0; j < 4; ++j) *(short8*)&A[r][c0 + j * 8] = cvt8(p + j * 8);
        } else {
            const u16* p = (const u16*)Ap + (size_t)(row0 + r) * 256 + c0;
#pragma unroll
            for (int j = 0; j < 4; ++j) *(short8*)&A[r][c0 + j * 8] = *(const short8*)(p + j * 8);
        }
    }
    __syncthreads();
    const int lane = t & 63, wave = t >> 6;
    const int lr = lane & 15, kg = lane >> 4;
    const int col0 = blockIdx.y * 128 + wave * 32;
    f32x4 acc[2][2] = {};
    for (int k0 = 0; k0 < 256; k0 += 32) {
        int k = k0 + kg * 8;
        short8 a0 = *(const short8*)&A[lr][k];
        short8 a1 = *(const short8*)&A[16 + lr][k];
#pragma unroll
        for (int nt = 0; nt < 2; ++nt) {
            short8 b = *(const short8*)(W + (size_t)(col0 + nt * 16 + lr) * 256 + k);
            acc[0][nt] = __builtin_amdgcn_mfma_f32_16x16x32_bf16(a0, b, acc[0][nt], 0, 0, 0);
            acc[1][nt] = __builtin_amdgcn_mfma_f32_16x16x32_bf16(a1, b, acc[1][nt], 0, 0, 0);
        }
    }
#pragma unroll
    for (int nt = 0; nt < 2; ++nt) {
        int n = col0 + nt * 16 + lr;
        float bn = bias[n];
#pragma unroll
        for (int mt = 0; mt < 2; ++mt) {
            int m0 = row0 + mt * 16 + kg * 4;
#pragma unroll
            for (int r = 0; r < 4; ++r) {
                float v = acc[mt][nt][r] + bn;
                if constexpr (ACT == 0) ((u16*)Cp)[(size_t)(m0 + r) * 256 + n] = f2bf(v);
                else                    ((float*)Cp)[(size_t)(m0 + r) * 256 + n] = tanhf(v);
            }
        }
    }
}

// ---------------- gemm_tn: tn for ALL 4 layers (pure input function, hoisted) ----------------
// grid (256, 2, 4): z = layer. A = t_att[z,7] (f32), W = wtn[z].
__global__ __launch_bounds__(256, 4) void gemm_tn(
    const float* __restrict__ t_att, const u16* __restrict__ Wbf,
    const float* __restrict__ btn, u16* __restrict__ tn_all)
{
    __shared__ __align__(16) u16 A[32][LPAD];
    const int t = threadIdx.x;
    const int row0 = blockIdx.x * 32;
    const int L = blockIdx.z;
    {
        int r = t >> 3, c0 = (t & 7) * 32;
        const float* p = t_att + ((size_t)L * 8 + 7) * BH + (size_t)(row0 + r) * 256 + c0;
#pragma unroll
        for (int j = 0; j < 4; ++j) *(short8*)&A[r][c0 + j * 8] = cvt8(p + j * 8);
    }
    __syncthreads();
    const int lane = t & 63, wave = t >> 6;
    const int lr = lane & 15, kg = lane >> 4;
    const int col0 = blockIdx.y * 128 + wave * 32;
    const u16* W = Wbf + (size_t)(1 + L) * 65536;
    f32x4 acc[2][2] = {};
    for (int k0 = 0; k0 < 256; k0 += 32) {
        int k = k0 + kg * 8;
        short8 a0 = *(const short8*)&A[lr][k];
        short8 a1 = *(const short8*)&A[16 + lr][k];
#pragma unroll
        for (int nt = 0; nt < 2; ++nt) {
            short8 b = *(const short8*)(W + (size_t)(col0 + nt * 16 + lr) * 256 + k);
            acc[0][nt] = __builtin_amdgcn_mfma_f32_16x16x32_bf16(a0, b, acc[0][nt], 0, 0, 0);
            acc[1][nt] = __builtin_amdgcn_mfma_f32_16x16x32_bf16(a1, b, acc[1][nt], 0, 0, 0);
        }
    }
    u16* dst = tn_all + (size_t)L * BH;
#pragma unroll
    for (int nt = 0; nt < 2; ++nt) {
        int n = col0 + nt * 16 + lr;
        float bn = btn[L * 256 + n];
#pragma unroll
        for (int mt = 0; mt < 2; ++mt) {
            int m0 = row0 + mt * 16 + kg * 4;
#pragma unroll
            for (int r = 0; r < 4; ++r)
                dst[(size_t)(m0 + r) * 256 + n] = f2bf(acc[mt][nt][r] + bn);
        }
    }
}

// ---------------- gemm_sn: s_next only (recurrence-dependent half of old dual) ----------------
__global__ __launch_bounds__(256, 4) void gemm_sn(
    const u16* __restrict__ Scur, const u16* __restrict__ Wsn,
    const float* __restrict__ bsn_l, u16* __restrict__ sn_g)
{
    __shared__ __align__(16) u16 A[32][LPAD];
    const int t = threadIdx.x;
    const int row0 = blockIdx.x * 32;
    {
        int r = t >> 3, c0 = (t & 7) * 32;
        const u16* p = Scur + (size_t)(row0 + r) * 256 + c0;
#pragma unroll
        for (int j = 0; j < 4; ++j) *(short8*)&A[r][c0 + j * 8] = *(const short8*)(p + j * 8);
    }
    __syncthreads();
    const int lane = t & 63, wave = t >> 6;
    const int lr = lane & 15, kg = lane >> 4;
    const int col0 = blockIdx.y * 128 + wave * 32;
    f32x4 acc[2][2] = {};
    for (int k0 = 0; k0 < 256; k0 += 32) {
        int k = k0 + kg * 8;
        short8 a0 = *(const short8*)&A[lr][k];
        short8 a1 = *(const short8*)&A[16 + lr][k];
#pragma unroll
        for (int nt = 0; nt < 2; ++nt) {
            short8 b = *(const short8*)(Wsn + (size_t)(col0 + nt * 16 + lr) * 256 + k);
            acc[0][nt] = __builtin_amdgcn_mfma_f32_16x16x32_bf16(a0, b, acc[0][nt], 0, 0, 0);
            acc[1][nt] = __builtin_amdgcn_mfma_f32_16x16x32_bf16(a1, b, acc[1][nt], 0, 0, 0);
        }
    }
#pragma unroll
    for (int nt = 0; nt < 2; ++nt) {
        int n = col0 + nt * 16 + lr;
        float bn = bsn_l[n];
#pragma unroll
        for (int mt = 0; mt < 2; ++mt) {
            int m0 = row0 + mt * 16 + kg * 4;
#pragma unroll
            for (int r = 0; r < 4; ++r)
                sn_g[(size_t)(m0 + r) * 256 + n] = f2bf(acc[mt][nt][r] + bn);
        }
    }
}

// ---------------- gemm_triple: 3 GEMMs + gated combine -> S_{i+1} ----------------
__global__ __launch_bounds__(256, 2) void gemm_triple(
    const u16* __restrict__ Tf, const u16* __restrict__ Sf,
    const u16* __restrict__ Wt3, const u16* __restrict__ Ws1, const u16* __restrict__ Ws3,
    const float* __restrict__ b1p, const float* __restrict__ b2p, const float* __restrict__ b3p,
    u16* __restrict__ Sout)
{
    __shared__ __align__(16) u16 At[32][LPAD];
    __shared__ __align__(16) u16 As[32][LPAD];
    const int t = threadIdx.x;
    const int row0 = blockIdx.x * 32;
    {
        int r = t >> 3, c0 = (t & 7) * 32;
        size_t off = (size_t)(row0 + r) * 256 + c0;
#pragma unroll
        for (int j = 0; j < 4; ++j) {
            *(short8*)&At[r][c0 + j * 8] = *(const short8*)(Tf + off + j * 8);
            *(short8*)&As[r][c0 + j * 8] = *(const short8*)(Sf + off + j * 8);
        }
    }
    __syncthreads();
    const int lane = t & 63, wave = t >> 6;
    const int lr = lane & 15, kg = lane >> 4;
    const int col0 = blockIdx.y * 128 + wave * 32;
    f32x4 aT[2][2] = {}, aG[2][2] = {}, aS[2][2] = {};
    for (int k0 = 0; k0 < 256; k0 += 32) {
        int k = k0 + kg * 8;
        short8 at0 = *(const short8*)&At[lr][k];
        short8 at1 = *(const short8*)&At[16 + lr][k];
        short8 as0 = *(const short8*)&As[lr][k];
        short8 as1 = *(const short8*)&As[16 + lr][k];
#pragma unroll
        for (int nt = 0; nt < 2; ++nt) {
            size_t wo = (size_t)(col0 + nt * 16 + lr) * 256 + k;
            short8 bT = *(const short8*)(Wt3 + wo);
            short8 bG = *(const short8*)(Ws1 + wo);
            short8 bS = *(const short8*)(Ws3 + wo);
            aT[0][nt] = __builtin_amdgcn_mfma_f32_16x16x32_bf16(at0, bT, aT[0][nt], 0, 0, 0);
            aT[1][nt] = __builtin_amdgcn_mfma_f32_16x16x32_bf16(at1, bT, aT[1][nt], 0, 0, 0);
            aG[0][nt] = __builtin_amdgcn_mfma_f32_16x16x32_bf16(as0, bG, aG[0][nt], 0, 0, 0);
            aG[1][nt] = __builtin_amdgcn_mfma_f32_16x16x32_bf16(as1, bG, aG[1][nt], 0, 0, 0);
            aS[0][nt] = __builtin_amdgcn_mfma_f32_16x16x32_bf16(as0, bS, aS[0][nt], 0, 0, 0);
            aS[1][nt] = __builtin_amdgcn_mfma_f32_16x16x32_bf16(as1, bS, aS[1][nt], 0, 0, 0);
        }
    }
#pragma unroll
    for (int nt = 0; nt < 2; ++nt) {
        int n = col0 + nt * 16 + lr;
        float bb1 = b1p[n], bb2 = b2p[n], bb3 = b3p[n];
#pragma unroll
        for (int mt = 0; mt < 2; ++mt) {
            int m0 = row0 + mt * 16 + kg * 4;
#pragma unroll
            for (int r = 0; r < 4; ++r) {
                float gv = sigmoidf_(aG[mt][nt][r] + bb2);
                float v = gv * (aS[mt][nt][r] + bb3) + (1.f - gv) * (aT[mt][nt][r] + bb1);
                Sout[(size_t)(m0 + r) * 256 + n] = f2bf(v);
            }
        }
    }
}

// ---------------- attention: one wave per row, plain loads, default occupancy ----------------
template<int I>
__global__ __launch_bounds__(256) void attn_k(
    const float* __restrict__ t_att, const float* __restrict__ s_att,
    const u16* __restrict__ S_hist,
    const u16* __restrict__ sn_g, const u16* __restrict__ tn_g,
    u16* __restrict__ tf_g, u16* __restrict__ sf_g)
{
    const int lane = threadIdx.x & 63;
    const int row = blockIdx.x * 4 + (threadIdx.x >> 6);
    const size_t ro = (size_t)row * 256 + lane * 4;
    const float scale = 0.0625f;  // 1/sqrt(256)

    const float* sa = s_att + (size_t)I * 8 * BH + ro;
    const float* ta = t_att + (size_t)I * 8 * BH + ro;

    us4 snu = *(const us4*)(sn_g + ro);
    us4 tnu = *(const us4*)(tn_g + ro);
    us4 scu = *(const us4*)(S_hist + (size_t)I * BH + ro);
    us4 shu[I > 0 ? I : 1];
#pragma unroll
    for (int jj = 0; jj < I; ++jj) shu[jj] = *(const us4*)(S_hist + (size_t)jj * BH + ro);

    f32x4 sav[7], tav[8], tsp[I > 0 ? I : 1];
#pragma unroll
    for (int kk = 0; kk < 7; ++kk) sav[kk] = *(const f32x4*)(sa + (size_t)(kk + 1) * BH);
#pragma unroll
    for (int kk = 0; kk < 8; ++kk) tav[kk] = *(const f32x4*)(ta + (size_t)kk * BH);
#pragma unroll
    for (int jj = 0; jj < I; ++jj) tsp[jj] = *(const f32x4*)(t_att + ((size_t)jj * 8 + 7) * BH + ro);

    float sn[4], tn[4], Sc[4];
#pragma unroll
    for (int j = 0; j < 4; ++j) { sn[j] = bf2f(snu[j]); tn[j] = bf2f(tnu[j]); Sc[j] = bf2f(scu[j]); }

    constexpr int NV = 9 + I;
    float v[NV];
#pragma unroll
    for (int kk = 0; kk < 7; ++kk) v[kk] = dot4(sav[kk], sn);
    v[7] = Sc[0] * sn[0] + Sc[1] * sn[1] + Sc[2] * sn[2] + Sc[3] * sn[3];
#pragma unroll
    for (int jj = 0; jj < I; ++jj) v[8 + jj] = dot4(tsp[jj], tn);
    v[8 + I] = dot4(tav[7], tn);

    // single 6-level butterfly over all NV values
#pragma unroll
    for (int o = 32; o > 0; o >>= 1)
#pragma unroll
        for (int u = 0; u < NV; ++u) v[u] += __shfl_xor(v[u], o);

    // temporal softmax + T_fusion
    float m = v[0] * scale;
#pragma unroll
    for (int kk = 1; kk < 8; ++kk) m = fmaxf(m, v[kk] * scale);
    float w8[8], den = 0.f;
#pragma unroll
    for (int kk = 0; kk < 8; ++kk) { w8[kk] = __expf(v[kk] * scale - m); den += w8[kk]; }
    float inv = 1.f / den;

    float Tt[4] = {0.f, 0.f, 0.f, 0.f};
#pragma unroll
    for (int kk = 0; kk < 8; ++kk)
#pragma unroll
        for (int j = 0; j < 4; ++j) Tt[j] += w8[kk] * tav[kk][j];
    us4 ot;
#pragma unroll
    for (int j = 0; j < 4; ++j) {
        float g = sigmoidf_(tn[j]);
        ot[j] = f2bf(tav[7][j] * g + (1.f - g) * Tt[j] * inv);
    }
    *(us4*)(tf_g + ro) = ot;

    // spatial softmax: keys = [zeros x (7-I), t_att[0,7]..t_att[I,7]]
    float ms = fmaxf(0.f, v[8 + I] * scale);
#pragma unroll
    for (int jj = 0; jj < I; ++jj) ms = fmaxf(ms, v[8 + jj] * scale);
    float dens = (float)(7 - I) * __expf(-ms);
    float St[4];
    {
        float w = __expf(v[8 + I] * scale - ms);
        dens += w;
#pragma unroll
        for (int j = 0; j < 4; ++j) St[j] = w * Sc[j];
    }
#pragma unroll
    for (int jj = 0; jj < I; ++jj) {
        float w = __expf(v[8 + jj] * scale - ms);
        dens += w;
#pragma unroll
        for (int j = 0; j < 4; ++j) St[j] += w * bf2f(shu[jj][j]);
    }
    float invs = 1.f / dens;
    us4 os;
#pragma unroll
    for (int j = 0; j < 4; ++j) {
        float g = sigmoidf_(sn[j]);
        os[j] = f2bf(Sc[j] * g + (1.f - g) * St[j] * invs);
    }
    *(us4*)(sf_g + ro) = os;
}

extern "C" void kernel_launch(void* const* d_in, const int* in_sizes, int n_in,
                              void* d_out, int out_size, void* d_ws, size_t ws_size,
                              hipStream_t stream)
{
    (void)in_sizes; (void)n_in; (void)out_size; (void)ws_size;
    const float* x       = (const float*)d_in[0];
    const float* t_att   = (const float*)d_in[1];
    const float* s_att   = (const float*)d_in[2];
    const float* embed_w = (const float*)d_in[3];
    const float* embed_b = (const float*)d_in[4];
    const float* wtn     = (const float*)d_in[5];
    const float* btn     = (const float*)d_in[6];
    const float* wsn     = (const float*)d_in[7];
    const float* bsn     = (const float*)d_in[8];
    const float* wt      = (const float*)d_in[9];
    const float* bt      = (const float*)d_in[10];
    const float* ws_in   = (const float*)d_in[11];
    const float* bs      = (const float*)d_in[12];
    const float* out_w   = (const float*)d_in[13];
    const float* out_b   = (const float*)d_in[14];

    u16* wsp    = (u16*)d_ws;
    u16* Wbf    = wsp;                       // 22 * 65536 u16
    u16* S_hist = wsp + (size_t)22 * 65536;  // 5 * BH
    u16* sn_g   = S_hist + 5 * BH;           // BH
    u16* tn_all = sn_g + BH;                 // 4 * BH
    u16* tf_g   = tn_all + 4 * BH;           // BH
    u16* sf_g   = tf_g + BH;                 // BH

    convert_weights<<<1408, 256, 0, stream>>>(embed_w, wtn, wsn, wt, ws_in, out_w, Wbf);

    dim3 g2(256, 2);

    // hoisted: tn for all 4 layers (pure input function, off the critical path)
    gemm_tn<<<dim3(256, 2, 4), 256, 0, stream>>>(t_att, Wbf, btn, tn_all);

    // S0 = x @ embed_w^T + embed_b
    gemm_one<true, 0><<<g2, 256, 0, stream>>>(x, Wbf, embed_b, S_hist);

    for (int i = 0; i < 4; ++i) {
        gemm_sn<<<g2, 256, 0, stream>>>(
            S_hist + (size_t)i * BH, Wbf + (size_t)(5 + i) * 65536,
            bsn + i * 256, sn_g);

        const u16* tn_i = tn_all + (size_t)i * BH;
        switch (i) {
            case 0: attn_k<0><<<BATCH / 4, 256, 0, stream>>>(t_att, s_att, S_hist, sn_g, tn_i, tf_g, sf_g); break;
            case 1: attn_k<1><<<BATCH / 4, 256, 0, stream>>>(t_att, s_att, S_hist, sn_g, tn_i, tf_g, sf_g); break;
            case 2: attn_k<2><<<BATCH / 4, 256, 0, stream>>>(t_att, s_att, S_hist, sn_g, tn_i, tf_g, sf_g); break;
            case 3: attn_k<3><<<BATCH / 4, 256, 0, stream>>>(t_att, s_att, S_hist, sn_g, tn_i, tf_g, sf_g); break;
        }

        gemm_triple<<<g2, 256, 0, stream>>>(
            tf_g, sf_g,
            Wbf + (size_t)(9 + i) * 65536,
            Wbf + (size_t)(13 + i) * 65536,
            Wbf + (size_t)(17 + i) * 65536,
            bt + i * 768 + 512, bs + i * 768, bs + i * 768 + 512,
            S_hist + (size_t)(i + 1) * BH);
    }

    // out = tanh(S4 @ out_w^T + out_b), f32
    gemm_one<false, 1><<<g2, 256, 0, stream>>>(
        S_hist + (size_t)4 * BH, Wbf + (size_t)21 * 65536, out_b, (float*)d_out);
}

// Round 19
// 265.702 us; speedup vs baseline: 1.0102x; 1.0102x over previous
//
#include <hip/hip_runtime.h>
#include <cmath>

typedef __attribute__((ext_vector_type(8))) short short8;
typedef __attribute__((ext_vector_type(4))) float f32x4;
typedef __attribute__((ext_vector_type(4))) unsigned short us4;
typedef unsigned short u16;

#define BATCH 8192
static constexpr size_t BH = (size_t)BATCH * 256;
#define LPAD 264  // u16 LDS row stride (528 B)

__device__ __forceinline__ u16 f2bf(float f) {
    union { float f; unsigned u; } v; v.f = f;
    unsigned r = v.u + 0x7FFFu + ((v.u >> 16) & 1u);
    return (u16)(r >> 16);
}
__device__ __forceinline__ float bf2f(u16 u) {
    union { unsigned u; float f; } v; v.u = ((unsigned)u) << 16;
    return v.f;
}
__device__ __forceinline__ float sigmoidf_(float x) {
    return 1.f / (1.f + __expf(-x));
}
__device__ __forceinline__ short8 cvt8(const float* p) {
    f32x4 lo = *(const f32x4*)p, hi = *(const f32x4*)(p + 4);
    short8 t;
    t[0] = (short)f2bf(lo[0]); t[1] = (short)f2bf(lo[1]);
    t[2] = (short)f2bf(lo[2]); t[3] = (short)f2bf(lo[3]);
    t[4] = (short)f2bf(hi[0]); t[5] = (short)f2bf(hi[1]);
    t[6] = (short)f2bf(hi[2]); t[7] = (short)f2bf(hi[3]);
    return t;
}
__device__ __forceinline__ float dot4(const f32x4& a, const float* b) {
    return a[0] * b[0] + a[1] * b[1] + a[2] * b[2] + a[3] * b[3];
}

// ---------------- weight conversion ----------------
// dst layout (u16 units, 65536 per chunk):
//  c0: embed_w | c1..4: wtn[l] | c5..8: wsn[l] | c9..12: wt[l][512:768]
//  c13..16: ws[l][0:256] | c17..20: ws[l][512:768] | c21: out_w
__global__ __launch_bounds__(256) void convert_weights(
    const float* __restrict__ embed_w, const float* __restrict__ wtn,
    const float* __restrict__ wsn, const float* __restrict__ wt,
    const float* __restrict__ ws, const float* __restrict__ out_w,
    u16* __restrict__ dst)
{
    int idx = blockIdx.x * 256 + threadIdx.x;
    int e = idx * 4;
    if (e >= 22 * 65536) return;
    int c = e >> 16, o = e & 65535;
    const float* src;
    if (c == 0)      src = embed_w + o;
    else if (c < 5)  src = wtn + (size_t)(c - 1) * 65536 + o;
    else if (c < 9)  src = wsn + (size_t)(c - 5) * 65536 + o;
    else if (c < 13) src = wt + (size_t)(c - 9) * 768 * 256 + 512 * 256 + o;
    else if (c < 17) src = ws + (size_t)(c - 13) * 768 * 256 + o;
    else if (c < 21) src = ws + (size_t)(c - 17) * 768 * 256 + 512 * 256 + o;
    else             src = out_w + o;
    f32x4 v = *(const f32x4*)src;
    us4 r;
#pragma unroll
    for (int j = 0; j < 4; ++j) r[j] = f2bf(v[j]);
    *(us4*)(dst + e) = r;
}

// ---------------- gemm_one: C[8192,256] = A @ W^T + b ----------------
// block 256 thr (4 waves): M=32 (row0=bx*32), N=128 (col0=by*128); wave w -> 32 cols.
// A staged once in LDS; W streamed from L2 (weights amortized over 32 rows).
template<bool A_F32, int ACT>
__global__ __launch_bounds__(256, 4) void gemm_one(
    const void* __restrict__ Ap, const u16* __restrict__ W,
    const float* __restrict__ bias, void* __restrict__ Cp)
{
    __shared__ __align__(16) u16 A[32][LPAD];
    const int t = threadIdx.x;
    const int row0 = blockIdx.x * 32;
    {
        int r = t >> 3, c0 = (t & 7) * 32;
        if constexpr (A_F32) {
            const float* p = (const float*)Ap + (size_t)(row0 + r) * 256 + c0;
#pragma unroll
            for (int j = 0; j < 4; ++j) *(short8*)&A[r][c0 + j * 8] = cvt8(p + j * 8);
        } else {
            const u16* p = (const u16*)Ap + (size_t)(row0 + r) * 256 + c0;
#pragma unroll
            for (int j = 0; j < 4; ++j) *(short8*)&A[r][c0 + j * 8] = *(const short8*)(p + j * 8);
        }
    }
    __syncthreads();
    const int lane = t & 63, wave = t >> 6;
    const int lr = lane & 15, kg = lane >> 4;
    const int col0 = blockIdx.y * 128 + wave * 32;
    f32x4 acc[2][2] = {};
    for (int k0 = 0; k0 < 256; k0 += 32) {
        int k = k0 + kg * 8;
        short8 a0 = *(const short8*)&A[lr][k];
        short8 a1 = *(const short8*)&A[16 + lr][k];
#pragma unroll
        for (int nt = 0; nt < 2; ++nt) {
            short8 b = *(const short8*)(W + (size_t)(col0 + nt * 16 + lr) * 256 + k);
            acc[0][nt] = __builtin_amdgcn_mfma_f32_16x16x32_bf16(a0, b, acc[0][nt], 0, 0, 0);
            acc[1][nt] = __builtin_amdgcn_mfma_f32_16x16x32_bf16(a1, b, acc[1][nt], 0, 0, 0);
        }
    }
#pragma unroll
    for (int nt = 0; nt < 2; ++nt) {
        int n = col0 + nt * 16 + lr;
        float bn = bias[n];
#pragma unroll
        for (int mt = 0; mt < 2; ++mt) {
            int m0 = row0 + mt * 16 + kg * 4;
#pragma unroll
            for (int r = 0; r < 4; ++r) {
                float v = acc[mt][nt][r] + bn;
                if constexpr (ACT == 0) ((u16*)Cp)[(size_t)(m0 + r) * 256 + n] = f2bf(v);
                else                    ((float*)Cp)[(size_t)(m0 + r) * 256 + n] = tanhf(v);
            }
        }
    }
}

// ---------------- gemm_dual: z=0 -> s_next (bf16 A), z=1 -> t_next (f32 A) ----------------
__global__ __launch_bounds__(256, 4) void gemm_dual(
    const u16* __restrict__ Scur, const float* __restrict__ Tlast,
    const u16* __restrict__ Wsn, const u16* __restrict__ Wtn,
    const float* __restrict__ bsn_l, const float* __restrict__ btn_l,
    u16* __restrict__ sn_g, u16* __restrict__ tn_g)
{
    __shared__ __align__(16) u16 A[32][LPAD];
    const int t = threadIdx.x;
    const int row0 = blockIdx.x * 32;
    const int g = blockIdx.z;
    {
        int r = t >> 3, c0 = (t & 7) * 32;
        if (g) {
            const float* p = Tlast + (size_t)(row0 + r) * 256 + c0;
#pragma unroll
            for (int j = 0; j < 4; ++j) *(short8*)&A[r][c0 + j * 8] = cvt8(p + j * 8);
        } else {
            const u16* p = Scur + (size_t)(row0 + r) * 256 + c0;
#pragma unroll
            for (int j = 0; j < 4; ++j) *(short8*)&A[r][c0 + j * 8] = *(const short8*)(p + j * 8);
        }
    }
    __syncthreads();
    const int lane = t & 63, wave = t >> 6;
    const int lr = lane & 15, kg = lane >> 4;
    const int col0 = blockIdx.y * 128 + wave * 32;
    const u16* W = g ? Wtn : Wsn;
    f32x4 acc[2][2] = {};
    for (int k0 = 0; k0 < 256; k0 += 32) {
        int k = k0 + kg * 8;
        short8 a0 = *(const short8*)&A[lr][k];
        short8 a1 = *(const short8*)&A[16 + lr][k];
#pragma unroll
        for (int nt = 0; nt < 2; ++nt) {
            short8 b = *(const short8*)(W + (size_t)(col0 + nt * 16 + lr) * 256 + k);
            acc[0][nt] = __builtin_amdgcn_mfma_f32_16x16x32_bf16(a0, b, acc[0][nt], 0, 0, 0);
            acc[1][nt] = __builtin_amdgcn_mfma_f32_16x16x32_bf16(a1, b, acc[1][nt], 0, 0, 0);
        }
    }
    const float* bias = g ? btn_l : bsn_l;
    u16* dst = g ? tn_g : sn_g;
#pragma unroll
    for (int nt = 0; nt < 2; ++nt) {
        int n = col0 + nt * 16 + lr;
        float bn = bias[n];
#pragma unroll
        for (int mt = 0; mt < 2; ++mt) {
            int m0 = row0 + mt * 16 + kg * 4;
#pragma unroll
            for (int r = 0; r < 4; ++r)
                dst[(size_t)(m0 + r) * 256 + n] = f2bf(acc[mt][nt][r] + bn);
        }
    }
}

// ---------------- gemm_triple: 3 GEMMs + gated combine -> S_{i+1} ----------------
__global__ __launch_bounds__(256, 2) void gemm_triple(
    const u16* __restrict__ Tf, const u16* __restrict__ Sf,
    const u16* __restrict__ Wt3, const u16* __restrict__ Ws1, const u16* __restrict__ Ws3,
    const float* __restrict__ b1p, const float* __restrict__ b2p, const float* __restrict__ b3p,
    u16* __restrict__ Sout)
{
    __shared__ __align__(16) u16 At[32][LPAD];
    __shared__ __align__(16) u16 As[32][LPAD];
    const int t = threadIdx.x;
    const int row0 = blockIdx.x * 32;
    {
        int r = t >> 3, c0 = (t & 7) * 32;
        size_t off = (size_t)(row0 + r) * 256 + c0;
#pragma unroll
        for (int j = 0; j < 4; ++j) {
            *(short8*)&At[r][c0 + j * 8] = *(const short8*)(Tf + off + j * 8);
            *(short8*)&As[r][c0 + j * 8] = *(const short8*)(Sf + off + j * 8);
        }
    }
    __syncthreads();
    const int lane = t & 63, wave = t >> 6;
    const int lr = lane & 15, kg = lane >> 4;
    const int col0 = blockIdx.y * 128 + wave * 32;
    f32x4 aT[2][2] = {}, aG[2][2] = {}, aS[2][2] = {};
    for (int k0 = 0; k0 < 256; k0 += 32) {
        int k = k0 + kg * 8;
        short8 at0 = *(const short8*)&At[lr][k];
        short8 at1 = *(const short8*)&At[16 + lr][k];
        short8 as0 = *(const short8*)&As[lr][k];
        short8 as1 = *(const short8*)&As[16 + lr][k];
#pragma unroll
        for (int nt = 0; nt < 2; ++nt) {
            size_t wo = (size_t)(col0 + nt * 16 + lr) * 256 + k;
            short8 bT = *(const short8*)(Wt3 + wo);
            short8 bG = *(const short8*)(Ws1 + wo);
            short8 bS = *(const short8*)(Ws3 + wo);
            aT[0][nt] = __builtin_amdgcn_mfma_f32_16x16x32_bf16(at0, bT, aT[0][nt], 0, 0, 0);
            aT[1][nt] = __builtin_amdgcn_mfma_f32_16x16x32_bf16(at1, bT, aT[1][nt], 0, 0, 0);
            aG[0][nt] = __builtin_amdgcn_mfma_f32_16x16x32_bf16(as0, bG, aG[0][nt], 0, 0, 0);
            aG[1][nt] = __builtin_amdgcn_mfma_f32_16x16x32_bf16(as1, bG, aG[1][nt], 0, 0, 0);
            aS[0][nt] = __builtin_amdgcn_mfma_f32_16x16x32_bf16(as0, bS, aS[0][nt], 0, 0, 0);
            aS[1][nt] = __builtin_amdgcn_mfma_f32_16x16x32_bf16(as1, bS, aS[1][nt], 0, 0, 0);
        }
    }
#pragma unroll
    for (int nt = 0; nt < 2; ++nt) {
        int n = col0 + nt * 16 + lr;
        float bb1 = b1p[n], bb2 = b2p[n], bb3 = b3p[n];
#pragma unroll
        for (int mt = 0; mt < 2; ++mt) {
            int m0 = row0 + mt * 16 + kg * 4;
#pragma unroll
            for (int r = 0; r < 4; ++r) {
                float gv = sigmoidf_(aG[mt][nt][r] + bb2);
                float v = gv * (aS[mt][nt][r] + bb3) + (1.f - gv) * (aT[mt][nt][r] + bb1);
                Sout[(size_t)(m0 + r) * 256 + n] = f2bf(v);
            }
        }
    }
}

// ---------------- attention: one wave per row, plain loads, default occupancy ----------------
// grid 2048 x 256 thr (4 rows/block). R1/R15/R17-proven TLP regime +
// single merged butterfly (one 6-level chain for all 9+I logits).
template<int I>
__global__ __launch_bounds__(256) void attn_k(
    const float* __restrict__ t_att, const float* __restrict__ s_att,
    const u16* __restrict__ S_hist,
    const u16* __restrict__ sn_g, const u16* __restrict__ tn_g,
    u16* __restrict__ tf_g, u16* __restrict__ sf_g)
{
    const int lane = threadIdx.x & 63;
    const int row = blockIdx.x * 4 + (threadIdx.x >> 6);
    const size_t ro = (size_t)row * 256 + lane * 4;
    const float scale = 0.0625f;  // 1/sqrt(256)

    const float* sa = s_att + (size_t)I * 8 * BH + ro;
    const float* ta = t_att + (size_t)I * 8 * BH + ro;

    us4 snu = *(const us4*)(sn_g + ro);
    us4 tnu = *(const us4*)(tn_g + ro);
    us4 scu = *(const us4*)(S_hist + (size_t)I * BH + ro);
    us4 shu[I > 0 ? I : 1];
#pragma unroll
    for (int jj = 0; jj < I; ++jj) shu[jj] = *(const us4*)(S_hist + (size_t)jj * BH + ro);

    f32x4 sav[7], tav[8], tsp[I > 0 ? I : 1];
#pragma unroll
    for (int kk = 0; kk < 7; ++kk) sav[kk] = *(const f32x4*)(sa + (size_t)(kk + 1) * BH);
#pragma unroll
    for (int kk = 0; kk < 8; ++kk) tav[kk] = *(const f32x4*)(ta + (size_t)kk * BH);
#pragma unroll
    for (int jj = 0; jj < I; ++jj) tsp[jj] = *(const f32x4*)(t_att + ((size_t)jj * 8 + 7) * BH + ro);

    float sn[4], tn[4], Sc[4];
#pragma unroll
    for (int j = 0; j < 4; ++j) { sn[j] = bf2f(snu[j]); tn[j] = bf2f(tnu[j]); Sc[j] = bf2f(scu[j]); }

    constexpr int NV = 9 + I;
    float v[NV];
#pragma unroll
    for (int kk = 0; kk < 7; ++kk) v[kk] = dot4(sav[kk], sn);
    v[7] = Sc[0] * sn[0] + Sc[1] * sn[1] + Sc[2] * sn[2] + Sc[3] * sn[3];
#pragma unroll
    for (int jj = 0; jj < I; ++jj) v[8 + jj] = dot4(tsp[jj], tn);
    v[8 + I] = dot4(tav[7], tn);

    // single 6-level butterfly over all NV values
#pragma unroll
    for (int o = 32; o > 0; o >>= 1)
#pragma unroll
        for (int u = 0; u < NV; ++u) v[u] += __shfl_xor(v[u], o);

    // temporal softmax + T_fusion
    float m = v[0] * scale;
#pragma unroll
    for (int kk = 1; kk < 8; ++kk) m = fmaxf(m, v[kk] * scale);
    float w8[8], den = 0.f;
#pragma unroll
    for (int kk = 0; kk < 8; ++kk) { w8[kk] = __expf(v[kk] * scale - m); den += w8[kk]; }
    float inv = 1.f / den;

    float Tt[4] = {0.f, 0.f, 0.f, 0.f};
#pragma unroll
    for (int kk = 0; kk < 8; ++kk)
#pragma unroll
        for (int j = 0; j < 4; ++j) Tt[j] += w8[kk] * tav[kk][j];
    us4 ot;
#pragma unroll
    for (int j = 0; j < 4; ++j) {
        float g = sigmoidf_(tn[j]);
        ot[j] = f2bf(tav[7][j] * g + (1.f - g) * Tt[j] * inv);
    }
    *(us4*)(tf_g + ro) = ot;

    // spatial softmax: keys = [zeros x (7-I), t_att[0,7]..t_att[I,7]]
    float ms = fmaxf(0.f, v[8 + I] * scale);
#pragma unroll
    for (int jj = 0; jj < I; ++jj) ms = fmaxf(ms, v[8 + jj] * scale);
    float dens = (float)(7 - I) * __expf(-ms);
    float St[4];
    {
        float w = __expf(v[8 + I] * scale - ms);
        dens += w;
#pragma unroll
        for (int j = 0; j < 4; ++j) St[j] = w * Sc[j];
    }
#pragma unroll
    for (int jj = 0; jj < I; ++jj) {
        float w = __expf(v[8 + jj] * scale - ms);
        dens += w;
#pragma unroll
        for (int j = 0; j < 4; ++j) St[j] += w * bf2f(shu[jj][j]);
    }
    float invs = 1.f / dens;
    us4 os;
#pragma unroll
    for (int j = 0; j < 4; ++j) {
        float g = sigmoidf_(sn[j]);
        os[j] = f2bf(Sc[j] * g + (1.f - g) * St[j] * invs);
    }
    *(us4*)(sf_g + ro) = os;
}

extern "C" void kernel_launch(void* const* d_in, const int* in_sizes, int n_in,
                              void* d_out, int out_size, void* d_ws, size_t ws_size,
                              hipStream_t stream)
{
    (void)in_sizes; (void)n_in; (void)out_size; (void)ws_size;
    const float* x       = (const float*)d_in[0];
    const float* t_att   = (const float*)d_in[1];
    const float* s_att   = (const float*)d_in[2];
    const float* embed_w = (const float*)d_in[3];
    const float* embed_b = (const float*)d_in[4];
    const float* wtn     = (const float*)d_in[5];
    const float* btn     = (const float*)d_in[6];
    const float* wsn     = (const float*)d_in[7];
    const float* bsn     = (const float*)d_in[8];
    const float* wt      = (const float*)d_in[9];
    const float* bt      = (const float*)d_in[10];
    const float* ws_in   = (const float*)d_in[11];
    const float* bs      = (const float*)d_in[12];
    const float* out_w   = (const float*)d_in[13];
    const float* out_b   = (const float*)d_in[14];

    u16* wsp    = (u16*)d_ws;
    u16* Wbf    = wsp;                       // 22 * 65536 u16
    u16* S_hist = wsp + (size_t)22 * 65536;  // 5 * BH
    u16* sn_g   = S_hist + 5 * BH;
    u16* tn_g   = sn_g + BH;
    u16* tf_g   = tn_g + BH;
    u16* sf_g   = tf_g + BH;

    convert_weights<<<1408, 256, 0, stream>>>(embed_w, wtn, wsn, wt, ws_in, out_w, Wbf);

    dim3 g2(256, 2);

    // S0 = x @ embed_w^T + embed_b
    gemm_one<true, 0><<<g2, 256, 0, stream>>>(x, Wbf, embed_b, S_hist);

    for (int i = 0; i < 4; ++i) {
        gemm_dual<<<dim3(256, 2, 2), 256, 0, stream>>>(
            S_hist + (size_t)i * BH, t_att + ((size_t)i * 8 + 7) * BH,
            Wbf + (size_t)(5 + i) * 65536, Wbf + (size_t)(1 + i) * 65536,
            bsn + i * 256, btn + i * 256, sn_g, tn_g);

        switch (i) {
            case 0: attn_k<0><<<BATCH / 4, 256, 0, stream>>>(t_att, s_att, S_hist, sn_g, tn_g, tf_g, sf_g); break;
            case 1: attn_k<1><<<BATCH / 4, 256, 0, stream>>>(t_att, s_att, S_hist, sn_g, tn_g, tf_g, sf_g); break;
            case 2: attn_k<2><<<BATCH / 4, 256, 0, stream>>>(t_att, s_att, S_hist, sn_g, tn_g, tf_g, sf_g); break;
            case 3: attn_k<3><<<BATCH / 4, 256, 0, stream>>>(t_att, s_att, S_hist, sn_g, tn_g, tf_g, sf_g); break;
        }

        gemm_triple<<<g2, 256, 0, stream>>>(
            tf_g, sf_g,
            Wbf + (size_t)(9 + i) * 65536,
            Wbf + (size_t)(13 + i) * 65536,
            Wbf + (size_t)(17 + i) * 65536,
            bt + i * 768 + 512, bs + i * 768, bs + i * 768 + 512,
            S_hist + (size_t)(i + 1) * BH);
    }

    // out = tanh(S4 @ out_w^T + out_b), f32
    gemm_one<false, 1><<<g2, 256, 0, stream>>>(
        S_hist + (size_t)4 * BH, Wbf + (size_t)21 * 65536, out_b, (float*)d_out);
}